// Round 1
// baseline (251.007 us; speedup 1.0000x reference)
//
#include <hip/hip_runtime.h>
#include <float.h>

#define N_TOK   32768
#define DIM     64
#define K_CODES 8192
#define HWSZ    1024
#define CHW     65536
#define NELEM   2097152

typedef short  bf16x8 __attribute__((ext_vector_type(8)));
typedef float  f32x16 __attribute__((ext_vector_type(16)));

static __device__ __forceinline__ unsigned short f2bf(float x) {
    unsigned u = __float_as_uint(x);
    unsigned r = u + 0x7FFFu + ((u >> 16) & 1u);
    return (unsigned short)(r >> 16);
}
static __device__ __forceinline__ float bf2f(unsigned short h) {
    return __uint_as_float(((unsigned)h) << 16);
}

// ------- prep_e: emb -> frag-ordered bf16 hi/lo blob + ||e||^2 + ws zeroing --
__global__ __launch_bounds__(256) void prep_e(const float* __restrict__ emb,
                                              unsigned short* __restrict__ blob,
                                              float* __restrict__ eng,
                                              unsigned long long* __restrict__ packed,
                                              int* __restrict__ cnt_i,
                                              float* __restrict__ sums) {
    __shared__ float part[512];
    const int gid = blockIdx.x * 256 + threadIdx.x;   // 0..32767
    packed[gid] = ~0ull;                              // init for atomicMin
    if (gid < K_CODES) cnt_i[gid] = 0;
    if (gid < 2) sums[gid] = 0.f;

    int tile = blockIdx.x;
    #pragma unroll
    for (int u0 = 0; u0 < 2; ++u0) {
        int u = threadIdx.x + u0 * 256;
        int s = u >> 7, h = (u >> 6) & 1, n = u & 63;
        const float* src = emb + (tile * 64 + n) * 64 + s * 16 + h * 8;
        float4 v0 = *(const float4*)src;
        float4 v1 = *(const float4*)(src + 4);
        float x[8] = {v0.x, v0.y, v0.z, v0.w, v1.x, v1.y, v1.z, v1.w};
        unsigned short hi[8], lo[8];
        float ss = 0.f;
        #pragma unroll
        for (int j = 0; j < 8; ++j) {
            hi[j] = f2bf(x[j]);
            lo[j] = f2bf(x[j] - bf2f(hi[j]));
            ss += x[j] * x[j];
        }
        part[u] = ss;
        unsigned short* dhi = blob + (size_t)tile * 8192 + ((s * 2 + 0) * 2 + h) * 512 + n * 8;
        unsigned short* dlo = blob + (size_t)tile * 8192 + ((s * 2 + 1) * 2 + h) * 512 + n * 8;
        uint4 ph, pl;
        ph.x = (unsigned)hi[0] | ((unsigned)hi[1] << 16);
        ph.y = (unsigned)hi[2] | ((unsigned)hi[3] << 16);
        ph.z = (unsigned)hi[4] | ((unsigned)hi[5] << 16);
        ph.w = (unsigned)hi[6] | ((unsigned)hi[7] << 16);
        pl.x = (unsigned)lo[0] | ((unsigned)lo[1] << 16);
        pl.y = (unsigned)lo[2] | ((unsigned)lo[3] << 16);
        pl.z = (unsigned)lo[4] | ((unsigned)lo[5] << 16);
        pl.w = (unsigned)lo[6] | ((unsigned)lo[7] << 16);
        *(uint4*)dhi = ph;
        *(uint4*)dlo = pl;
    }
    __syncthreads();
    if (threadIdx.x < 64) {
        float s = 0.f;
        #pragma unroll
        for (int j = 0; j < 8; ++j) s += part[threadIdx.x + j * 64];
        eng[tile * 64 + threadIdx.x] = s;
    }
}

// ---------------- argmin: swapped operands (codes=M, tokens=N) ---------------
// Block: 64 tokens, 4 waves = 2 token-tiles x 2 code-halves.
// Wave tile per kt: 32 codes x 32 tokens, single f32x16 acc.
// acc init = ||e||^2 (fragment order); A = emb hi/lo, B = (-2z) hi/lo.
// After MFMAs acc[r] IS the distance -> 1 running (val,idx) pair per lane.
__global__ __launch_bounds__(256, 4) void vq_argmin(const float* __restrict__ z,
                                                    const unsigned short* __restrict__ blob,
                                                    const float* __restrict__ eng,
                                                    unsigned long long* __restrict__ packed) {
    __shared__ __align__(16) unsigned short zh[64 * 72];
    __shared__ __align__(16) unsigned short zl[64 * 72];
    __shared__ unsigned long long red[64 * 2];

    const int tid  = threadIdx.x;
    const int lane = tid & 63;
    const int wid  = tid >> 6;           // 0..3
    const int wr   = wid >> 1;           // token tile 0/1
    const int wc   = wid & 1;            // code half 0/1
    const int l31  = lane & 31, h = lane >> 5;

    const int tb = blockIdx.x & 511;     // token-tile id 0..511
    const int ks = blockIdx.x >> 9;      // K split 0/1
    const int n0 = tb * 64;
    const int zbase = (n0 >> 10) * CHW + (n0 & 1023);
    const int t0 = ks * 64, t1 = t0 + 64;   // kt range (64-code tiles)
    const int wcb = (wc * 32 + l31) * 8;

    // ---- stage -2*z as bf16 hi/lo (64 tokens x 64 dims) ----
    {
        int f4 = tid & 15;               // 16 float4 = 64 tokens per channel
        int c0 = tid >> 4;               // 0..15
        #pragma unroll
        for (int r = 0; r < 4; ++r) {
            int c = c0 * 4 + r;
            float4 v = *(const float4*)(z + zbase + c * HWSZ + f4 * 4);
            float x[4] = {v.x, v.y, v.z, v.w};
            #pragma unroll
            for (int e = 0; e < 4; ++e) {
                int t = f4 * 4 + e;
                float xs = -2.0f * x[e];
                unsigned short hi = f2bf(xs);
                zh[t * 72 + c] = hi;
                zl[t * 72 + c] = f2bf(xs - bf2f(hi));
            }
        }
    }
    __syncthreads();

    // ---- resident token fragments (B operand): token = wr*32 + l31 ----
    bf16x8 Tf[4][2];
    {
        int row = wr * 32 + l31;
        #pragma unroll
        for (int s = 0; s < 4; ++s) {
            Tf[s][0] = *(const bf16x8*)(&zh[row * 72 + s * 16 + h * 8]);
            Tf[s][1] = *(const bf16x8*)(&zl[row * 72 + s * 16 + h * 8]);
        }
    }

    float minv = FLT_MAX;
    int   mini = 0;

    for (int kt = t0; kt < t1; ++kt) {
        // code fragments (A operand) for codes [kt*64 + wc*32, +32)
        bf16x8 Eh[4], El[4];
        const unsigned short* base = blob + (size_t)kt * 8192 + wcb;
        #pragma unroll
        for (int s = 0; s < 4; ++s) {
            Eh[s] = *(const bf16x8*)(base + (4 * s + h) * 512);
            El[s] = *(const bf16x8*)(base + (4 * s + 2 + h) * 512);
        }
        // acc init: ac[r] = eng[kt*64 + wc*32 + 4h + (r&3) + 8*(r>>2)]
        const float* ebase = eng + kt * 64 + wc * 32 + 4 * h;
        float4 e0 = *(const float4*)(ebase);
        float4 e1 = *(const float4*)(ebase + 8);
        float4 e2 = *(const float4*)(ebase + 16);
        float4 e3 = *(const float4*)(ebase + 24);
        f32x16 ac;
        ac[0]  = e0.x; ac[1]  = e0.y; ac[2]  = e0.z; ac[3]  = e0.w;
        ac[4]  = e1.x; ac[5]  = e1.y; ac[6]  = e1.z; ac[7]  = e1.w;
        ac[8]  = e2.x; ac[9]  = e2.y; ac[10] = e2.z; ac[11] = e2.w;
        ac[12] = e3.x; ac[13] = e3.y; ac[14] = e3.z; ac[15] = e3.w;
        #pragma unroll
        for (int s = 0; s < 4; ++s) {
            ac = __builtin_amdgcn_mfma_f32_32x32x16_bf16(El[s], Tf[s][0], ac, 0, 0, 0);
            ac = __builtin_amdgcn_mfma_f32_32x32x16_bf16(Eh[s], Tf[s][1], ac, 0, 0, 0);
            ac = __builtin_amdgcn_mfma_f32_32x32x16_bf16(Eh[s], Tf[s][0], ac, 0, 0, 0);
        }
        const int cb = kt * 64 + wc * 32 + 4 * h;
        #pragma unroll
        for (int r = 0; r < 16; ++r) {
            int code = cb + (r & 3) + 8 * (r >> 2);
            if (ac[r] < minv) { minv = ac[r]; mini = code; }
        }
    }

    // ---- merge h halves (same token, disjoint code rows) ----
    unsigned u = __float_as_uint(minv);
    u = (u & 0x80000000u) ? ~u : (u | 0x80000000u);
    unsigned long long key = ((unsigned long long)u << 32) | (unsigned)mini;
    unsigned long long o = __shfl_xor(key, 32, 64);
    if (o < key) key = o;
    if (h == 0) red[(wr * 32 + l31) * 2 + wc] = key;
    __syncthreads();
    if (tid < 64) {
        unsigned long long a = red[tid * 2], b = red[tid * 2 + 1];
        unsigned long long m = (b < a) ? b : a;
        atomicMin(&packed[n0 + tid], m);
    }
}

// ------- zq_loss: idx, histogram, z_q_st, loss, z_t, emao init ---------------
__global__ __launch_bounds__(256) void zq_loss(const float* __restrict__ z,
                                               const float* __restrict__ emb,
                                               const float* __restrict__ ema_w,
                                               const unsigned long long* __restrict__ packed,
                                               float* __restrict__ zq_out,
                                               float* __restrict__ idx_out,
                                               int* __restrict__ idx_i32,
                                               int* __restrict__ cnt_i,
                                               float* __restrict__ loss_sum,
                                               float* __restrict__ z_t,
                                               float* __restrict__ emao_out) {
    const int tid = threadIdx.x;
    const int n0  = blockIdx.x * 64;
    const int t   = tid >> 2, q = tid & 3;
    const int n   = n0 + t;
    const int idx = (int)(packed[n] & 0xFFFFFFFFull);
    if (q == 0) {
        idx_out[n] = (float)idx;
        idx_i32[n] = idx;
        atomicAdd(&cnt_i[idx], 1);
    }
    // emao init: 4 strided elements per thread, coalesced scalar stores
    {
        int g = blockIdx.x * 256 + tid;         // 0..131071
        #pragma unroll
        for (int j = 0; j < 4; ++j) {
            int i = g + j * 131072;
            emao_out[i] = 0.99f * ema_w[i];
        }
    }
    const int b = n >> 10, hw = n & 1023;
    const float* er = emb + idx * 64 + q * 16;
    float4 e0 = *(const float4*)er, e1 = *(const float4*)(er + 4);
    float4 e2 = *(const float4*)(er + 8), e3 = *(const float4*)(er + 12);
    float ev[16] = {e0.x, e0.y, e0.z, e0.w, e1.x, e1.y, e1.z, e1.w,
                    e2.x, e2.y, e2.z, e2.w, e3.x, e3.y, e3.z, e3.w};
    float lsum = 0.f;
    #pragma unroll
    for (int j = 0; j < 16; ++j) {
        int c = q * 16 + j;
        float zv = z[b * CHW + c * HWSZ + hw];
        float dd = ev[j] - zv;
        zq_out[b * CHW + c * HWSZ + hw] = zv + dd;
        if (z_t) z_t[n * 64 + c] = zv;
        lsum += dd * dd;
    }
    #pragma unroll
    for (int m = 32; m >= 1; m >>= 1) lsum += __shfl_xor(lsum, m, 64);
    if ((tid & 63) == 0) atomicAdd(loss_sum, lsum);
}

// ------- scan_cs: prefix over cnt -> cursor, cs_norm out, loss out -----------
__global__ __launch_bounds__(1024) void scan_cs(const int* __restrict__ cnt_i,
                                                const float* __restrict__ csize,
                                                const float* __restrict__ loss_sum,
                                                int* __restrict__ cursor,
                                                float* __restrict__ csn_out,
                                                float* __restrict__ loss_out) {
    __shared__ int   sc[1024];
    __shared__ float sf[1024];
    const int tid = threadIdx.x;
    int v[8], part = 0;
    float cv[8], fpart = 0.f;
    #pragma unroll
    for (int j = 0; j < 8; ++j) { v[j] = cnt_i[tid * 8 + j]; part += v[j]; }
    #pragma unroll
    for (int j = 0; j < 8; ++j) {
        cv[j] = 0.99f * csize[tid * 8 + j] + 0.01f * (float)v[j];
        fpart += cv[j];
    }
    sc[tid] = part;
    sf[tid] = fpart;
    __syncthreads();
    for (int off = 1; off < 1024; off <<= 1) {
        int add = (tid >= off) ? sc[tid - off] : 0;
        __syncthreads();
        sc[tid] += add;
        __syncthreads();
    }
    int run = sc[tid] - part;
    #pragma unroll
    for (int j = 0; j < 8; ++j) {
        cursor[tid * 8 + j] = run;
        run += v[j];
    }
    for (int off = 512; off >= 1; off >>= 1) {
        if (tid < off) sf[tid] += sf[tid + off];
        __syncthreads();
    }
    float denom = sf[0] + (float)(K_CODES * 1e-5);
    #pragma unroll
    for (int j = 0; j < 8; ++j) csn_out[tid * 8 + j] = (cv[j] + 1e-5f) / denom;
    if (tid == 0) *loss_out = 0.25f * (*loss_sum) * (1.0f / (float)NELEM);
}

// ------- scatter: tokens into code-sorted order, with code tags --------------
__global__ __launch_bounds__(256) void scatter_kernel(const int* __restrict__ idx_i32,
                                                      int* __restrict__ cursor,
                                                      int* __restrict__ tok_of,
                                                      int* __restrict__ code_of) {
    int t = blockIdx.x * 256 + threadIdx.x;
    int k = idx_i32[t];
    int pos = atomicAdd(&cursor[k], 1);
    tok_of[pos] = t;
    code_of[pos] = k;
}

// ------- ema_acc: balanced 64-position chunks, pipelined loads ---------------
__global__ __launch_bounds__(256) void ema_acc(const float* __restrict__ z,
                                               const float* __restrict__ z_t,
                                               const int* __restrict__ tok_of,
                                               const int* __restrict__ code_of,
                                               float* __restrict__ emao_out) {
    const int wv   = (blockIdx.x * 256 + threadIdx.x) >> 6;   // 0..511
    const int lane = threadIdx.x & 63;
    const int pos0 = wv * 64;
    const int tok  = tok_of[pos0 + lane];
    const int cod  = code_of[pos0 + lane];
    float acc = 0.f;
    #pragma unroll
    for (int g = 0; g < 8; ++g) {
        int tk[8], kk[8];
        #pragma unroll
        for (int j = 0; j < 8; ++j) {
            tk[j] = __shfl(tok, g * 8 + j, 64);
            kk[j] = __shfl(cod, g * 8 + j, 64);
        }
        float v[8];
        if (z_t) {
            #pragma unroll
            for (int j = 0; j < 8; ++j) v[j] = z_t[tk[j] * 64 + lane];
        } else {
            #pragma unroll
            for (int j = 0; j < 8; ++j)
                v[j] = z[(tk[j] >> 10) * CHW + lane * HWSZ + (tk[j] & 1023)];
        }
        int knext = (g < 7) ? __shfl(cod, g * 8 + 8, 64) : -1;
        #pragma unroll
        for (int j = 0; j < 8; ++j) {
            acc += v[j];
            int kn = (j < 7) ? kk[j + 1] : knext;
            if (kn != kk[j]) {
                atomicAdd(&emao_out[kk[j] * 64 + lane], 0.01f * acc);
                acc = 0.f;
            }
        }
    }
}

// ------- final_div: emb_out = emao / csn -------------------------------------
__global__ __launch_bounds__(256) void final_div(const float* __restrict__ emao_out,
                                                 const float* __restrict__ csn_out,
                                                 float* __restrict__ embo_out) {
    int g = blockIdx.x * 256 + threadIdx.x;
    embo_out[g] = emao_out[g] / csn_out[g >> 6];
}

extern "C" void kernel_launch(void* const* d_in, const int* in_sizes, int n_in,
                              void* d_out, int out_size, void* d_ws, size_t ws_size,
                              hipStream_t stream) {
    (void)in_sizes; (void)n_in; (void)out_size;
    const float* z     = (const float*)d_in[0];
    const float* emb   = (const float*)d_in[1];
    const float* ema_w = (const float*)d_in[2];
    const float* csize = (const float*)d_in[3];

    float* out      = (float*)d_out;
    float* zq_out   = out;
    float* loss_out = out + 2097152;
    float* idx_out  = out + 2097153;
    float* csn_out  = out + 2129921;
    float* emao_out = out + 2138113;
    float* embo_out = out + 2662401;

    char* wsb = (char*)d_ws;
    unsigned short*     blob    = (unsigned short*)(wsb);              // 2,097,152 B
    float*              eng     = (float*)(wsb + 2097152);             // 32 KB
    unsigned long long* packed  = (unsigned long long*)(wsb + 2129920);// 256 KB
    int*                code_of = (int*)(wsb + 2129920);               // aliases packed (dead after zq_loss)
    int*                idx_i32 = (int*)(wsb + 2392064);               // 128 KB
    int*                cnt_i   = (int*)(wsb + 2523136);               // 32 KB
    float*              sums    = (float*)(wsb + 2555904);             // 8 B
    int*                cursor  = (int*)(wsb + 2555920);               // 32 KB
    int*                tok_of  = (int*)(wsb + 2588688);               // 128 KB
    const size_t zt_off = 2719760;
    float* z_t = (ws_size >= zt_off + (size_t)NELEM * 4) ? (float*)(wsb + zt_off) : nullptr;

    prep_e<<<128, 256, 0, stream>>>(emb, blob, eng, packed, cnt_i, sums);
    vq_argmin<<<1024, 256, 0, stream>>>(z, blob, eng, packed);
    zq_loss<<<N_TOK / 64, 256, 0, stream>>>(z, emb, ema_w, packed, zq_out, idx_out,
                                            idx_i32, cnt_i, sums + 1, z_t, emao_out);
    scan_cs<<<1, 1024, 0, stream>>>(cnt_i, csize, sums + 1, cursor, csn_out, loss_out);
    scatter_kernel<<<N_TOK / 256, 256, 0, stream>>>(idx_i32, cursor, tok_of, code_of);
    ema_acc<<<128, 256, 0, stream>>>(z, z_t, tok_of, code_of, emao_out);
    final_div<<<K_CODES * DIM / 256, 256, 0, stream>>>(emao_out, csn_out, embo_out);
}

// Round 2
// 239.314 us; speedup vs baseline: 1.0489x; 1.0489x over previous
//
#include <hip/hip_runtime.h>
#include <float.h>

#define N_TOK   32768
#define DIM     64
#define K_CODES 8192
#define HWSZ    1024
#define CHW     65536
#define NELEM   2097152

typedef short  bf16x8 __attribute__((ext_vector_type(8)));
typedef float  f32x16 __attribute__((ext_vector_type(16)));

static __device__ __forceinline__ unsigned short f2bf(float x) {
    unsigned u = __float_as_uint(x);
    unsigned r = u + 0x7FFFu + ((u >> 16) & 1u);
    return (unsigned short)(r >> 16);
}
static __device__ __forceinline__ float bf2f(unsigned short h) {
    return __uint_as_float(((unsigned)h) << 16);
}

// ------- prep_e: emb -> frag-ordered bf16 hi/lo blob + ||e||^2 + ws zeroing --
__global__ __launch_bounds__(256) void prep_e(const float* __restrict__ emb,
                                              unsigned short* __restrict__ blob,
                                              float* __restrict__ eng,
                                              unsigned long long* __restrict__ packed,
                                              int* __restrict__ cnt_i,
                                              float* __restrict__ sums) {
    __shared__ float part[512];
    const int gid = blockIdx.x * 256 + threadIdx.x;   // 0..32767
    packed[gid] = ~0ull;                              // init for atomicMin
    if (gid < K_CODES) cnt_i[gid] = 0;
    if (gid < 2) sums[gid] = 0.f;

    int tile = blockIdx.x;
    #pragma unroll
    for (int u0 = 0; u0 < 2; ++u0) {
        int u = threadIdx.x + u0 * 256;
        int s = u >> 7, h = (u >> 6) & 1, n = u & 63;
        const float* src = emb + (tile * 64 + n) * 64 + s * 16 + h * 8;
        float4 v0 = *(const float4*)src;
        float4 v1 = *(const float4*)(src + 4);
        float x[8] = {v0.x, v0.y, v0.z, v0.w, v1.x, v1.y, v1.z, v1.w};
        unsigned short hi[8], lo[8];
        float ss = 0.f;
        #pragma unroll
        for (int j = 0; j < 8; ++j) {
            hi[j] = f2bf(x[j]);
            lo[j] = f2bf(x[j] - bf2f(hi[j]));
            ss += x[j] * x[j];
        }
        part[u] = ss;
        unsigned short* dhi = blob + (size_t)tile * 8192 + ((s * 2 + 0) * 2 + h) * 512 + n * 8;
        unsigned short* dlo = blob + (size_t)tile * 8192 + ((s * 2 + 1) * 2 + h) * 512 + n * 8;
        uint4 ph, pl;
        ph.x = (unsigned)hi[0] | ((unsigned)hi[1] << 16);
        ph.y = (unsigned)hi[2] | ((unsigned)hi[3] << 16);
        ph.z = (unsigned)hi[4] | ((unsigned)hi[5] << 16);
        ph.w = (unsigned)hi[6] | ((unsigned)hi[7] << 16);
        pl.x = (unsigned)lo[0] | ((unsigned)lo[1] << 16);
        pl.y = (unsigned)lo[2] | ((unsigned)lo[3] << 16);
        pl.z = (unsigned)lo[4] | ((unsigned)lo[5] << 16);
        pl.w = (unsigned)lo[6] | ((unsigned)lo[7] << 16);
        *(uint4*)dhi = ph;
        *(uint4*)dlo = pl;
    }
    __syncthreads();
    if (threadIdx.x < 64) {
        float s = 0.f;
        #pragma unroll
        for (int j = 0; j < 8; ++j) s += part[threadIdx.x + j * 64];
        eng[tile * 64 + threadIdx.x] = s;
    }
}

// ---------------- argmin: swapped operands, dual token-tile chains -----------
// Block: 64 tokens, 4 waves. Wave wid walks half-kt tiles hk = ks*128 + wid,
// step 4 (no barriers, waves desync). Per half-kt (32 codes):
//   - load 8 code frags (shared by both chains) + 4 eng float4
//   - 24 MFMAs: 2 independent chains (token tiles 0..31 / 32..63) x 4 s x 3
//   - acc init = ||e||^2 (fragment order) so acc IS the distance
//   - epilogue: cmp/sel only (1 running (val,idx) per lane per chain)
__global__ __launch_bounds__(256, 3) void vq_argmin(const float* __restrict__ z,
                                                    const unsigned short* __restrict__ blob,
                                                    const float* __restrict__ eng,
                                                    unsigned long long* __restrict__ packed) {
    __shared__ __align__(16) unsigned short zh[64 * 72];
    __shared__ __align__(16) unsigned short zl[64 * 72];
    __shared__ unsigned long long red[64 * 4];

    const int tid  = threadIdx.x;
    const int lane = tid & 63;
    const int wid  = tid >> 6;           // 0..3
    const int l31  = lane & 31, h = lane >> 5;

    const int tb = blockIdx.x & 511;     // token-tile id 0..511
    const int ks = blockIdx.x >> 9;      // K split 0/1
    const int n0 = tb * 64;
    const int zbase = (n0 >> 10) * CHW + (n0 & 1023);

    // ---- stage -2*z as bf16 hi/lo (64 tokens x 64 dims) ----
    {
        int f4 = tid & 15;               // 16 float4 = 64 tokens per channel
        int c0 = tid >> 4;               // 0..15
        #pragma unroll
        for (int r = 0; r < 4; ++r) {
            int c = c0 * 4 + r;
            float4 v = *(const float4*)(z + zbase + c * HWSZ + f4 * 4);
            float x[4] = {v.x, v.y, v.z, v.w};
            #pragma unroll
            for (int e = 0; e < 4; ++e) {
                int t = f4 * 4 + e;
                float xs = -2.0f * x[e];
                unsigned short hi = f2bf(xs);
                zh[t * 72 + c] = hi;
                zl[t * 72 + c] = f2bf(xs - bf2f(hi));
            }
        }
    }
    __syncthreads();

    // ---- resident token fragments (B operand), both 32-token tiles ----
    bf16x8 T0h[4], T0l[4], T1h[4], T1l[4];
    {
        int r0 = l31;        // tile 0 token
        int r1 = 32 + l31;   // tile 1 token
        #pragma unroll
        for (int s = 0; s < 4; ++s) {
            T0h[s] = *(const bf16x8*)(&zh[r0 * 72 + s * 16 + h * 8]);
            T0l[s] = *(const bf16x8*)(&zl[r0 * 72 + s * 16 + h * 8]);
            T1h[s] = *(const bf16x8*)(&zh[r1 * 72 + s * 16 + h * 8]);
            T1l[s] = *(const bf16x8*)(&zl[r1 * 72 + s * 16 + h * 8]);
        }
    }

    float minv0 = FLT_MAX, minv1 = FLT_MAX;
    int   mini0 = 0,       mini1 = 0;

    const int hk0 = ks * 128 + wid, hk1 = ks * 128 + 128;
    for (int hk = hk0; hk < hk1; hk += 4) {
        // code fragments (A operand) for 32 codes of this half-kt
        bf16x8 Eh[4], El[4];
        const unsigned short* base = blob + (size_t)(hk >> 1) * 8192 + ((hk & 1) * 32 + l31) * 8;
        #pragma unroll
        for (int s = 0; s < 4; ++s) {
            Eh[s] = *(const bf16x8*)(base + (4 * s + h) * 512);
            El[s] = *(const bf16x8*)(base + (4 * s + 2 + h) * 512);
        }
        // acc init: ac[r] = eng[cb + (r&3) + 8*(r>>2)], shared by both chains
        const int cb = (hk >> 1) * 64 + (hk & 1) * 32 + 4 * h;
        const float* ebase = eng + cb;
        float4 e0 = *(const float4*)(ebase);
        float4 e1 = *(const float4*)(ebase + 8);
        float4 e2 = *(const float4*)(ebase + 16);
        float4 e3 = *(const float4*)(ebase + 24);
        f32x16 ac0, ac1;
        ac0[0]  = e0.x; ac0[1]  = e0.y; ac0[2]  = e0.z; ac0[3]  = e0.w;
        ac0[4]  = e1.x; ac0[5]  = e1.y; ac0[6]  = e1.z; ac0[7]  = e1.w;
        ac0[8]  = e2.x; ac0[9]  = e2.y; ac0[10] = e2.z; ac0[11] = e2.w;
        ac0[12] = e3.x; ac0[13] = e3.y; ac0[14] = e3.z; ac0[15] = e3.w;
        ac1 = ac0;
        #pragma unroll
        for (int s = 0; s < 4; ++s) {
            ac0 = __builtin_amdgcn_mfma_f32_32x32x16_bf16(El[s], T0h[s], ac0, 0, 0, 0);
            ac1 = __builtin_amdgcn_mfma_f32_32x32x16_bf16(El[s], T1h[s], ac1, 0, 0, 0);
            ac0 = __builtin_amdgcn_mfma_f32_32x32x16_bf16(Eh[s], T0l[s], ac0, 0, 0, 0);
            ac1 = __builtin_amdgcn_mfma_f32_32x32x16_bf16(Eh[s], T1l[s], ac1, 0, 0, 0);
            ac0 = __builtin_amdgcn_mfma_f32_32x32x16_bf16(Eh[s], T0h[s], ac0, 0, 0, 0);
            ac1 = __builtin_amdgcn_mfma_f32_32x32x16_bf16(Eh[s], T1h[s], ac1, 0, 0, 0);
        }
        #pragma unroll
        for (int r = 0; r < 16; ++r) {
            int code = cb + (r & 3) + 8 * (r >> 2);
            if (ac0[r] < minv0) { minv0 = ac0[r]; mini0 = code; }
            if (ac1[r] < minv1) { minv1 = ac1[r]; mini1 = code; }
        }
    }

    // ---- merge h halves (same token, disjoint code rows), then waves ----
    unsigned u0 = __float_as_uint(minv0);
    u0 = (u0 & 0x80000000u) ? ~u0 : (u0 | 0x80000000u);
    unsigned long long k0 = ((unsigned long long)u0 << 32) | (unsigned)mini0;
    unsigned u1 = __float_as_uint(minv1);
    u1 = (u1 & 0x80000000u) ? ~u1 : (u1 | 0x80000000u);
    unsigned long long k1 = ((unsigned long long)u1 << 32) | (unsigned)mini1;
    unsigned long long o0 = __shfl_xor(k0, 32, 64);
    if (o0 < k0) k0 = o0;
    unsigned long long o1 = __shfl_xor(k1, 32, 64);
    if (o1 < k1) k1 = o1;
    if (h == 0) {
        red[l31 * 4 + wid]        = k0;
        red[(32 + l31) * 4 + wid] = k1;
    }
    __syncthreads();
    if (tid < 64) {
        unsigned long long a = red[tid * 4], b = red[tid * 4 + 1];
        unsigned long long c = red[tid * 4 + 2], d = red[tid * 4 + 3];
        unsigned long long m = (b < a) ? b : a;
        if (c < m) m = c;
        if (d < m) m = d;
        atomicMin(&packed[n0 + tid], m);
    }
}

// ------- zq_loss: idx, histogram, z_q_st, loss, z_t, emao init ---------------
__global__ __launch_bounds__(256) void zq_loss(const float* __restrict__ z,
                                               const float* __restrict__ emb,
                                               const float* __restrict__ ema_w,
                                               const unsigned long long* __restrict__ packed,
                                               float* __restrict__ zq_out,
                                               float* __restrict__ idx_out,
                                               int* __restrict__ idx_i32,
                                               int* __restrict__ cnt_i,
                                               float* __restrict__ loss_sum,
                                               float* __restrict__ z_t,
                                               float* __restrict__ emao_out) {
    const int tid = threadIdx.x;
    const int n0  = blockIdx.x * 64;
    const int t   = tid >> 2, q = tid & 3;
    const int n   = n0 + t;
    const int idx = (int)(packed[n] & 0xFFFFFFFFull);
    if (q == 0) {
        idx_out[n] = (float)idx;
        idx_i32[n] = idx;
        atomicAdd(&cnt_i[idx], 1);
    }
    // emao init: 4 strided elements per thread, coalesced scalar stores
    {
        int g = blockIdx.x * 256 + tid;         // 0..131071
        #pragma unroll
        for (int j = 0; j < 4; ++j) {
            int i = g + j * 131072;
            emao_out[i] = 0.99f * ema_w[i];
        }
    }
    const int b = n >> 10, hw = n & 1023;
    const float* er = emb + idx * 64 + q * 16;
    float4 e0 = *(const float4*)er, e1 = *(const float4*)(er + 4);
    float4 e2 = *(const float4*)(er + 8), e3 = *(const float4*)(er + 12);
    float ev[16] = {e0.x, e0.y, e0.z, e0.w, e1.x, e1.y, e1.z, e1.w,
                    e2.x, e2.y, e2.z, e2.w, e3.x, e3.y, e3.z, e3.w};
    float lsum = 0.f;
    #pragma unroll
    for (int j = 0; j < 16; ++j) {
        int c = q * 16 + j;
        float zv = z[b * CHW + c * HWSZ + hw];
        float dd = ev[j] - zv;
        zq_out[b * CHW + c * HWSZ + hw] = zv + dd;
        if (z_t) z_t[n * 64 + c] = zv;
        lsum += dd * dd;
    }
    #pragma unroll
    for (int m = 32; m >= 1; m >>= 1) lsum += __shfl_xor(lsum, m, 64);
    if ((tid & 63) == 0) atomicAdd(loss_sum, lsum);
}

// ------- scan_cs: prefix over cnt -> cursor, cs_norm out, loss out -----------
__global__ __launch_bounds__(1024) void scan_cs(const int* __restrict__ cnt_i,
                                                const float* __restrict__ csize,
                                                const float* __restrict__ loss_sum,
                                                int* __restrict__ cursor,
                                                float* __restrict__ csn_out,
                                                float* __restrict__ loss_out) {
    __shared__ int   sc[1024];
    __shared__ float sf[1024];
    const int tid = threadIdx.x;
    int v[8], part = 0;
    float cv[8], fpart = 0.f;
    #pragma unroll
    for (int j = 0; j < 8; ++j) { v[j] = cnt_i[tid * 8 + j]; part += v[j]; }
    #pragma unroll
    for (int j = 0; j < 8; ++j) {
        cv[j] = 0.99f * csize[tid * 8 + j] + 0.01f * (float)v[j];
        fpart += cv[j];
    }
    sc[tid] = part;
    sf[tid] = fpart;
    __syncthreads();
    for (int off = 1; off < 1024; off <<= 1) {
        int add = (tid >= off) ? sc[tid - off] : 0;
        __syncthreads();
        sc[tid] += add;
        __syncthreads();
    }
    int run = sc[tid] - part;
    #pragma unroll
    for (int j = 0; j < 8; ++j) {
        cursor[tid * 8 + j] = run;
        run += v[j];
    }
    for (int off = 512; off >= 1; off >>= 1) {
        if (tid < off) sf[tid] += sf[tid + off];
        __syncthreads();
    }
    float denom = sf[0] + (float)(K_CODES * 1e-5);
    #pragma unroll
    for (int j = 0; j < 8; ++j) csn_out[tid * 8 + j] = (cv[j] + 1e-5f) / denom;
    if (tid == 0) *loss_out = 0.25f * (*loss_sum) * (1.0f / (float)NELEM);
}

// ------- scatter: tokens into code-sorted order, with code tags --------------
__global__ __launch_bounds__(256) void scatter_kernel(const int* __restrict__ idx_i32,
                                                      int* __restrict__ cursor,
                                                      int* __restrict__ tok_of,
                                                      int* __restrict__ code_of) {
    int t = blockIdx.x * 256 + threadIdx.x;
    int k = idx_i32[t];
    int pos = atomicAdd(&cursor[k], 1);
    tok_of[pos] = t;
    code_of[pos] = k;
}

// ------- ema_acc: balanced 64-position chunks, pipelined loads ---------------
__global__ __launch_bounds__(256) void ema_acc(const float* __restrict__ z,
                                               const float* __restrict__ z_t,
                                               const int* __restrict__ tok_of,
                                               const int* __restrict__ code_of,
                                               float* __restrict__ emao_out) {
    const int wv   = (blockIdx.x * 256 + threadIdx.x) >> 6;   // 0..511
    const int lane = threadIdx.x & 63;
    const int pos0 = wv * 64;
    const int tok  = tok_of[pos0 + lane];
    const int cod  = code_of[pos0 + lane];
    float acc = 0.f;
    #pragma unroll
    for (int g = 0; g < 8; ++g) {
        int tk[8], kk[8];
        #pragma unroll
        for (int j = 0; j < 8; ++j) {
            tk[j] = __shfl(tok, g * 8 + j, 64);
            kk[j] = __shfl(cod, g * 8 + j, 64);
        }
        float v[8];
        if (z_t) {
            #pragma unroll
            for (int j = 0; j < 8; ++j) v[j] = z_t[tk[j] * 64 + lane];
        } else {
            #pragma unroll
            for (int j = 0; j < 8; ++j)
                v[j] = z[(tk[j] >> 10) * CHW + lane * HWSZ + (tk[j] & 1023)];
        }
        int knext = (g < 7) ? __shfl(cod, g * 8 + 8, 64) : -1;
        #pragma unroll
        for (int j = 0; j < 8; ++j) {
            acc += v[j];
            int kn = (j < 7) ? kk[j + 1] : knext;
            if (kn != kk[j]) {
                atomicAdd(&emao_out[kk[j] * 64 + lane], 0.01f * acc);
                acc = 0.f;
            }
        }
    }
}

// ------- final_div: emb_out = emao / csn -------------------------------------
__global__ __launch_bounds__(256) void final_div(const float* __restrict__ emao_out,
                                                 const float* __restrict__ csn_out,
                                                 float* __restrict__ embo_out) {
    int g = blockIdx.x * 256 + threadIdx.x;
    embo_out[g] = emao_out[g] / csn_out[g >> 6];
}

extern "C" void kernel_launch(void* const* d_in, const int* in_sizes, int n_in,
                              void* d_out, int out_size, void* d_ws, size_t ws_size,
                              hipStream_t stream) {
    (void)in_sizes; (void)n_in; (void)out_size;
    const float* z     = (const float*)d_in[0];
    const float* emb   = (const float*)d_in[1];
    const float* ema_w = (const float*)d_in[2];
    const float* csize = (const float*)d_in[3];

    float* out      = (float*)d_out;
    float* zq_out   = out;
    float* loss_out = out + 2097152;
    float* idx_out  = out + 2097153;
    float* csn_out  = out + 2129921;
    float* emao_out = out + 2138113;
    float* embo_out = out + 2662401;

    char* wsb = (char*)d_ws;
    unsigned short*     blob    = (unsigned short*)(wsb);              // 2,097,152 B
    float*              eng     = (float*)(wsb + 2097152);             // 32 KB
    unsigned long long* packed  = (unsigned long long*)(wsb + 2129920);// 256 KB
    int*                code_of = (int*)(wsb + 2129920);               // aliases packed (dead after zq_loss)
    int*                idx_i32 = (int*)(wsb + 2392064);               // 128 KB
    int*                cnt_i   = (int*)(wsb + 2523136);               // 32 KB
    float*              sums    = (float*)(wsb + 2555904);             // 8 B
    int*                cursor  = (int*)(wsb + 2555920);               // 32 KB
    int*                tok_of  = (int*)(wsb + 2588688);               // 128 KB
    const size_t zt_off = 2719760;
    float* z_t = (ws_size >= zt_off + (size_t)NELEM * 4) ? (float*)(wsb + zt_off) : nullptr;

    prep_e<<<128, 256, 0, stream>>>(emb, blob, eng, packed, cnt_i, sums);
    vq_argmin<<<1024, 256, 0, stream>>>(z, blob, eng, packed);
    zq_loss<<<N_TOK / 64, 256, 0, stream>>>(z, emb, ema_w, packed, zq_out, idx_out,
                                            idx_i32, cnt_i, sums + 1, z_t, emao_out);
    scan_cs<<<1, 1024, 0, stream>>>(cnt_i, csize, sums + 1, cursor, csn_out, loss_out);
    scatter_kernel<<<N_TOK / 256, 256, 0, stream>>>(idx_i32, cursor, tok_of, code_of);
    ema_acc<<<128, 256, 0, stream>>>(z, z_t, tok_of, code_of, emao_out);
    final_div<<<K_CODES * DIM / 256, 256, 0, stream>>>(emao_out, csn_out, embo_out);
}

// Round 4
// 223.954 us; speedup vs baseline: 1.1208x; 1.0686x over previous
//
#include <hip/hip_runtime.h>
#include <float.h>

#define N_TOK   32768
#define DIM     64
#define K_CODES 8192
#define HWSZ    1024
#define CHW     65536
#define NELEM   2097152

typedef short  bf16x8 __attribute__((ext_vector_type(8)));
typedef float  f32x16 __attribute__((ext_vector_type(16)));

static __device__ __forceinline__ unsigned short f2bf(float x) {
    unsigned u = __float_as_uint(x);
    unsigned r = u + 0x7FFFu + ((u >> 16) & 1u);
    return (unsigned short)(r >> 16);
}
static __device__ __forceinline__ float bf2f(unsigned short h) {
    return __uint_as_float(((unsigned)h) << 16);
}

// ------- prep_e: emb -> frag-ordered bf16 hi/lo blob + ||e||^2 + ws zeroing --
__global__ __launch_bounds__(256) void prep_e(const float* __restrict__ emb,
                                              unsigned short* __restrict__ blob,
                                              float* __restrict__ eng,
                                              unsigned long long* __restrict__ packed,
                                              int* __restrict__ cnt_i,
                                              float* __restrict__ sums) {
    __shared__ float part[512];
    const int gid = blockIdx.x * 256 + threadIdx.x;   // 0..32767
    packed[gid] = ~0ull;                              // init for atomicMin
    if (gid < K_CODES) cnt_i[gid] = 0;
    if (gid < 2) sums[gid] = 0.f;

    int tile = blockIdx.x;
    #pragma unroll
    for (int u0 = 0; u0 < 2; ++u0) {
        int u = threadIdx.x + u0 * 256;
        int s = u >> 7, h = (u >> 6) & 1, n = u & 63;
        const float* src = emb + (tile * 64 + n) * 64 + s * 16 + h * 8;
        float4 v0 = *(const float4*)src;
        float4 v1 = *(const float4*)(src + 4);
        float x[8] = {v0.x, v0.y, v0.z, v0.w, v1.x, v1.y, v1.z, v1.w};
        unsigned short hi[8], lo[8];
        float ss = 0.f;
        #pragma unroll
        for (int j = 0; j < 8; ++j) {
            hi[j] = f2bf(x[j]);
            lo[j] = f2bf(x[j] - bf2f(hi[j]));
            ss += x[j] * x[j];
        }
        part[u] = ss;
        unsigned short* dhi = blob + (size_t)tile * 8192 + ((s * 2 + 0) * 2 + h) * 512 + n * 8;
        unsigned short* dlo = blob + (size_t)tile * 8192 + ((s * 2 + 1) * 2 + h) * 512 + n * 8;
        uint4 ph, pl;
        ph.x = (unsigned)hi[0] | ((unsigned)hi[1] << 16);
        ph.y = (unsigned)hi[2] | ((unsigned)hi[3] << 16);
        ph.z = (unsigned)hi[4] | ((unsigned)hi[5] << 16);
        ph.w = (unsigned)hi[6] | ((unsigned)hi[7] << 16);
        pl.x = (unsigned)lo[0] | ((unsigned)lo[1] << 16);
        pl.y = (unsigned)lo[2] | ((unsigned)lo[3] << 16);
        pl.z = (unsigned)lo[4] | ((unsigned)lo[5] << 16);
        pl.w = (unsigned)lo[6] | ((unsigned)lo[7] << 16);
        *(uint4*)dhi = ph;
        *(uint4*)dlo = pl;
    }
    __syncthreads();
    if (threadIdx.x < 64) {
        float s = 0.f;
        #pragma unroll
        for (int j = 0; j < 8; ++j) s += part[threadIdx.x + j * 64];
        eng[tile * 64 + threadIdx.x] = s;
    }
}

// ---------------- argmin: software-pipelined, eng-seeded acc -----------------
// Block: 64 tokens, 4 waves. Wave wid walks half-kt tiles hk = ks*128+wid,+4.
// Body: seed acc from eng regs (round-2 numerics: eng is the MFMA C-seed) ->
//       issue next eng loads (g regs dead after seed) ->
//       24 MFMA (setprio) -> issue next E loads (E dead after MFMA issue) ->
//       epilogue (cmp/sel min only).
// Loads are unconditional: last-iteration over-read lands in adjacent mapped
// workspace (eng/packed), values unused.
__global__ __launch_bounds__(256, 3) void vq_argmin(const float* __restrict__ z,
                                                    const unsigned short* __restrict__ blob,
                                                    const float* __restrict__ eng,
                                                    unsigned long long* __restrict__ packed) {
    __shared__ __align__(16) unsigned short zh[64 * 72];
    __shared__ __align__(16) unsigned short zl[64 * 72];
    __shared__ unsigned long long red[64 * 4];

    const int tid  = threadIdx.x;
    const int lane = tid & 63;
    const int wid  = tid >> 6;           // 0..3
    const int l31  = lane & 31, h = lane >> 5;

    const int tb = blockIdx.x & 511;     // token-tile id 0..511
    const int ks = blockIdx.x >> 9;      // K split 0/1
    const int n0 = tb * 64;
    const int zbase = (n0 >> 10) * CHW + (n0 & 1023);

    // ---- stage -2*z as bf16 hi/lo (64 tokens x 64 dims) ----
    {
        int f4 = tid & 15;               // 16 float4 = 64 tokens per channel
        int c0 = tid >> 4;               // 0..15
        #pragma unroll
        for (int r = 0; r < 4; ++r) {
            int c = c0 * 4 + r;
            float4 v = *(const float4*)(z + zbase + c * HWSZ + f4 * 4);
            float x[4] = {v.x, v.y, v.z, v.w};
            #pragma unroll
            for (int e = 0; e < 4; ++e) {
                int t = f4 * 4 + e;
                float xs = -2.0f * x[e];
                unsigned short hi = f2bf(xs);
                zh[t * 72 + c] = hi;
                zl[t * 72 + c] = f2bf(xs - bf2f(hi));
            }
        }
    }
    __syncthreads();

    // ---- resident token fragments (B operand), both 32-token tiles ----
    bf16x8 T0h[4], T0l[4], T1h[4], T1l[4];
    {
        int r0 = l31;        // tile 0 token
        int r1 = 32 + l31;   // tile 1 token
        #pragma unroll
        for (int s = 0; s < 4; ++s) {
            T0h[s] = *(const bf16x8*)(&zh[r0 * 72 + s * 16 + h * 8]);
            T0l[s] = *(const bf16x8*)(&zl[r0 * 72 + s * 16 + h * 8]);
            T1h[s] = *(const bf16x8*)(&zh[r1 * 72 + s * 16 + h * 8]);
            T1l[s] = *(const bf16x8*)(&zl[r1 * 72 + s * 16 + h * 8]);
        }
    }

    const int hk0 = ks * 128 + wid;
    const unsigned short* bp = blob + (size_t)(hk0 >> 1) * 8192 + ((hk0 & 1) * 32 + l31) * 8;
    const float* ep = eng + (hk0 >> 1) * 64 + (hk0 & 1) * 32 + 4 * h;
    int scode = __builtin_amdgcn_readfirstlane((hk0 >> 1) * 64 + (hk0 & 1) * 32);

    // prologue: first tile's E frags + eng
    bf16x8 Eh[4], El[4];
    #pragma unroll
    for (int s = 0; s < 4; ++s) {
        Eh[s] = *(const bf16x8*)(bp + (4 * s + h) * 512);
        El[s] = *(const bf16x8*)(bp + (4 * s + 2 + h) * 512);
    }
    float4 g0 = *(const float4*)(ep);
    float4 g1 = *(const float4*)(ep + 8);
    float4 g2 = *(const float4*)(ep + 16);
    float4 g3 = *(const float4*)(ep + 24);

    float minv0 = FLT_MAX, minv1 = FLT_MAX;
    int   mini0 = 0,       mini1 = 0;

    for (int i = 0; i < 32; ++i) {
        // seed acc with ||e||^2 (round-2 numerics: eng is the MFMA C operand)
        f32x16 ac0, ac1;
        ac0[0]  = g0.x; ac0[1]  = g0.y; ac0[2]  = g0.z; ac0[3]  = g0.w;
        ac0[4]  = g1.x; ac0[5]  = g1.y; ac0[6]  = g1.z; ac0[7]  = g1.w;
        ac0[8]  = g2.x; ac0[9]  = g2.y; ac0[10] = g2.z; ac0[11] = g2.w;
        ac0[12] = g3.x; ac0[13] = g3.y; ac0[14] = g3.z; ac0[15] = g3.w;
        ac1 = ac0;

        // prefetch next tile's eng (g regs dead after seed); whole MFMA
        // cluster + epilogue covers the latency
        ep += 128;
        g0 = *(const float4*)(ep);
        g1 = *(const float4*)(ep + 8);
        g2 = *(const float4*)(ep + 16);
        g3 = *(const float4*)(ep + 24);

        __builtin_amdgcn_s_setprio(1);
        #pragma unroll
        for (int s = 0; s < 4; ++s) {
            ac0 = __builtin_amdgcn_mfma_f32_32x32x16_bf16(El[s], T0h[s], ac0, 0, 0, 0);
            ac1 = __builtin_amdgcn_mfma_f32_32x32x16_bf16(El[s], T1h[s], ac1, 0, 0, 0);
            ac0 = __builtin_amdgcn_mfma_f32_32x32x16_bf16(Eh[s], T0l[s], ac0, 0, 0, 0);
            ac1 = __builtin_amdgcn_mfma_f32_32x32x16_bf16(Eh[s], T1l[s], ac1, 0, 0, 0);
            ac0 = __builtin_amdgcn_mfma_f32_32x32x16_bf16(Eh[s], T0h[s], ac0, 0, 0, 0);
            ac1 = __builtin_amdgcn_mfma_f32_32x32x16_bf16(Eh[s], T1h[s], ac1, 0, 0, 0);
        }
        __builtin_amdgcn_s_setprio(0);

        // prefetch next tile's E frags (E regs dead once MFMAs issued)
        bp += 2 * 8192;   // hk += 4  ->  2 kt tiles of 8192 shorts
        #pragma unroll
        for (int s = 0; s < 4; ++s) {
            Eh[s] = *(const bf16x8*)(bp + (4 * s + h) * 512);
            El[s] = *(const bf16x8*)(bp + (4 * s + 2 + h) * 512);
        }

        // epilogue: acc IS the distance; min-update (cmp + 2 sel)
        #pragma unroll
        for (int r = 0; r < 16; ++r) {
            int code = scode + ((r & 3) + 8 * (r >> 2));
            if (ac0[r] < minv0) { minv0 = ac0[r]; mini0 = code; }
            if (ac1[r] < minv1) { minv1 = ac1[r]; mini1 = code; }
        }
        scode += 128;
    }
    mini0 += 4 * h;   // lane-dependent part of code, applied once
    mini1 += 4 * h;

    // ---- merge h halves (same token, disjoint code rows), then waves ----
    unsigned u0 = __float_as_uint(minv0);
    u0 = (u0 & 0x80000000u) ? ~u0 : (u0 | 0x80000000u);
    unsigned long long k0 = ((unsigned long long)u0 << 32) | (unsigned)mini0;
    unsigned u1 = __float_as_uint(minv1);
    u1 = (u1 & 0x80000000u) ? ~u1 : (u1 | 0x80000000u);
    unsigned long long k1 = ((unsigned long long)u1 << 32) | (unsigned)mini1;
    unsigned long long o0 = __shfl_xor(k0, 32, 64);
    if (o0 < k0) k0 = o0;
    unsigned long long o1 = __shfl_xor(k1, 32, 64);
    if (o1 < k1) k1 = o1;
    if (h == 0) {
        red[l31 * 4 + wid]        = k0;
        red[(32 + l31) * 4 + wid] = k1;
    }
    __syncthreads();
    if (tid < 64) {
        unsigned long long a = red[tid * 4], b = red[tid * 4 + 1];
        unsigned long long c = red[tid * 4 + 2], d = red[tid * 4 + 3];
        unsigned long long m = (b < a) ? b : a;
        if (c < m) m = c;
        if (d < m) m = d;
        atomicMin(&packed[n0 + tid], m);
    }
}

// ------- zq_loss: idx, histogram, z_q_st, loss, z_t, emao init ---------------
__global__ __launch_bounds__(256) void zq_loss(const float* __restrict__ z,
                                               const float* __restrict__ emb,
                                               const float* __restrict__ ema_w,
                                               const unsigned long long* __restrict__ packed,
                                               float* __restrict__ zq_out,
                                               float* __restrict__ idx_out,
                                               int* __restrict__ idx_i32,
                                               int* __restrict__ cnt_i,
                                               float* __restrict__ loss_sum,
                                               float* __restrict__ z_t,
                                               float* __restrict__ emao_out) {
    const int tid = threadIdx.x;
    const int n0  = blockIdx.x * 64;
    const int t   = tid >> 2, q = tid & 3;
    const int n   = n0 + t;
    const int idx = (int)(packed[n] & 0xFFFFFFFFull);
    if (q == 0) {
        idx_out[n] = (float)idx;
        idx_i32[n] = idx;
        atomicAdd(&cnt_i[idx], 1);
    }
    // emao init: 4 strided elements per thread, coalesced scalar stores
    {
        int g = blockIdx.x * 256 + tid;         // 0..131071
        #pragma unroll
        for (int j = 0; j < 4; ++j) {
            int i = g + j * 131072;
            emao_out[i] = 0.99f * ema_w[i];
        }
    }
    const int b = n >> 10, hw = n & 1023;
    const float* er = emb + idx * 64 + q * 16;
    float4 e0 = *(const float4*)er, e1 = *(const float4*)(er + 4);
    float4 e2 = *(const float4*)(er + 8), e3 = *(const float4*)(er + 12);
    float ev[16] = {e0.x, e0.y, e0.z, e0.w, e1.x, e1.y, e1.z, e1.w,
                    e2.x, e2.y, e2.z, e2.w, e3.x, e3.y, e3.z, e3.w};
    float lsum = 0.f;
    #pragma unroll
    for (int j = 0; j < 16; ++j) {
        int c = q * 16 + j;
        float zv = z[b * CHW + c * HWSZ + hw];
        float dd = ev[j] - zv;
        zq_out[b * CHW + c * HWSZ + hw] = zv + dd;
        if (z_t) z_t[n * 64 + c] = zv;
        lsum += dd * dd;
    }
    #pragma unroll
    for (int m = 32; m >= 1; m >>= 1) lsum += __shfl_xor(lsum, m, 64);
    if ((tid & 63) == 0) atomicAdd(loss_sum, lsum);
}

// ------- scan_cs: prefix over cnt -> cursor, cs_norm out, loss out -----------
__global__ __launch_bounds__(1024) void scan_cs(const int* __restrict__ cnt_i,
                                                const float* __restrict__ csize,
                                                const float* __restrict__ loss_sum,
                                                int* __restrict__ cursor,
                                                float* __restrict__ csn_out,
                                                float* __restrict__ loss_out) {
    __shared__ int   sc[1024];
    __shared__ float sf[1024];
    const int tid = threadIdx.x;
    int v[8], part = 0;
    float cv[8], fpart = 0.f;
    #pragma unroll
    for (int j = 0; j < 8; ++j) { v[j] = cnt_i[tid * 8 + j]; part += v[j]; }
    #pragma unroll
    for (int j = 0; j < 8; ++j) {
        cv[j] = 0.99f * csize[tid * 8 + j] + 0.01f * (float)v[j];
        fpart += cv[j];
    }
    sc[tid] = part;
    sf[tid] = fpart;
    __syncthreads();
    for (int off = 1; off < 1024; off <<= 1) {
        int add = (tid >= off) ? sc[tid - off] : 0;
        __syncthreads();
        sc[tid] += add;
        __syncthreads();
    }
    int run = sc[tid] - part;
    #pragma unroll
    for (int j = 0; j < 8; ++j) {
        cursor[tid * 8 + j] = run;
        run += v[j];
    }
    for (int off = 512; off >= 1; off >>= 1) {
        if (tid < off) sf[tid] += sf[tid + off];
        __syncthreads();
    }
    float denom = sf[0] + (float)(K_CODES * 1e-5);
    #pragma unroll
    for (int j = 0; j < 8; ++j) csn_out[tid * 8 + j] = (cv[j] + 1e-5f) / denom;
    if (tid == 0) *loss_out = 0.25f * (*loss_sum) * (1.0f / (float)NELEM);
}

// ------- scatter: tokens into code-sorted order, with code tags --------------
__global__ __launch_bounds__(256) void scatter_kernel(const int* __restrict__ idx_i32,
                                                      int* __restrict__ cursor,
                                                      int* __restrict__ tok_of,
                                                      int* __restrict__ code_of) {
    int t = blockIdx.x * 256 + threadIdx.x;
    int k = idx_i32[t];
    int pos = atomicAdd(&cursor[k], 1);
    tok_of[pos] = t;
    code_of[pos] = k;
}

// ------- ema_acc: balanced 64-position chunks, pipelined loads ---------------
__global__ __launch_bounds__(256) void ema_acc(const float* __restrict__ z,
                                               const float* __restrict__ z_t,
                                               const int* __restrict__ tok_of,
                                               const int* __restrict__ code_of,
                                               float* __restrict__ emao_out) {
    const int wv   = (blockIdx.x * 256 + threadIdx.x) >> 6;   // 0..511
    const int lane = threadIdx.x & 63;
    const int pos0 = wv * 64;
    const int tok  = tok_of[pos0 + lane];
    const int cod  = code_of[pos0 + lane];
    float acc = 0.f;
    #pragma unroll
    for (int g = 0; g < 8; ++g) {
        int tk[8], kk[8];
        #pragma unroll
        for (int j = 0; j < 8; ++j) {
            tk[j] = __shfl(tok, g * 8 + j, 64);
            kk[j] = __shfl(cod, g * 8 + j, 64);
        }
        float v[8];
        if (z_t) {
            #pragma unroll
            for (int j = 0; j < 8; ++j) v[j] = z_t[tk[j] * 64 + lane];
        } else {
            #pragma unroll
            for (int j = 0; j < 8; ++j)
                v[j] = z[(tk[j] >> 10) * CHW + lane * HWSZ + (tk[j] & 1023)];
        }
        int knext = (g < 7) ? __shfl(cod, g * 8 + 8, 64) : -1;
        #pragma unroll
        for (int j = 0; j < 8; ++j) {
            acc += v[j];
            int kn = (j < 7) ? kk[j + 1] : knext;
            if (kn != kk[j]) {
                atomicAdd(&emao_out[kk[j] * 64 + lane], 0.01f * acc);
                acc = 0.f;
            }
        }
    }
}

// ------- final_div: emb_out = emao / csn -------------------------------------
__global__ __launch_bounds__(256) void final_div(const float* __restrict__ emao_out,
                                                 const float* __restrict__ csn_out,
                                                 float* __restrict__ embo_out) {
    int g = blockIdx.x * 256 + threadIdx.x;
    embo_out[g] = emao_out[g] / csn_out[g >> 6];
}

extern "C" void kernel_launch(void* const* d_in, const int* in_sizes, int n_in,
                              void* d_out, int out_size, void* d_ws, size_t ws_size,
                              hipStream_t stream) {
    (void)in_sizes; (void)n_in; (void)out_size;
    const float* z     = (const float*)d_in[0];
    const float* emb   = (const float*)d_in[1];
    const float* ema_w = (const float*)d_in[2];
    const float* csize = (const float*)d_in[3];

    float* out      = (float*)d_out;
    float* zq_out   = out;
    float* loss_out = out + 2097152;
    float* idx_out  = out + 2097153;
    float* csn_out  = out + 2129921;
    float* emao_out = out + 2138113;
    float* embo_out = out + 2662401;

    char* wsb = (char*)d_ws;
    unsigned short*     blob    = (unsigned short*)(wsb);              // 2,097,152 B
    float*              eng     = (float*)(wsb + 2097152);             // 32 KB
    unsigned long long* packed  = (unsigned long long*)(wsb + 2129920);// 256 KB
    int*                code_of = (int*)(wsb + 2129920);               // aliases packed (dead after zq_loss)
    int*                idx_i32 = (int*)(wsb + 2392064);               // 128 KB
    int*                cnt_i   = (int*)(wsb + 2523136);               // 32 KB
    float*              sums    = (float*)(wsb + 2555904);             // 8 B
    int*                cursor  = (int*)(wsb + 2555920);               // 32 KB
    int*                tok_of  = (int*)(wsb + 2588688);               // 128 KB
    const size_t zt_off = 2719760;
    float* z_t = (ws_size >= zt_off + (size_t)NELEM * 4) ? (float*)(wsb + zt_off) : nullptr;

    prep_e<<<128, 256, 0, stream>>>(emb, blob, eng, packed, cnt_i, sums);
    vq_argmin<<<1024, 256, 0, stream>>>(z, blob, eng, packed);
    zq_loss<<<N_TOK / 64, 256, 0, stream>>>(z, emb, ema_w, packed, zq_out, idx_out,
                                            idx_i32, cnt_i, sums + 1, z_t, emao_out);
    scan_cs<<<1, 1024, 0, stream>>>(cnt_i, csize, sums + 1, cursor, csn_out, loss_out);
    scatter_kernel<<<N_TOK / 256, 256, 0, stream>>>(idx_i32, cursor, tok_of, code_of);
    ema_acc<<<128, 256, 0, stream>>>(z, z_t, tok_of, code_of, emao_out);
    final_div<<<K_CODES * DIM / 256, 256, 0, stream>>>(emao_out, csn_out, embo_out);
}